// Round 1
// baseline (141.851 us; speedup 1.0000x reference)
//
#include <hip/hip_runtime.h>

#define BM  64
#define DD  128
#define LDA 136   // bf16 elems per A row (+8 pad -> 2-way bank aliasing, free)
#define LDB 136

typedef __bf16 bf16x8 __attribute__((ext_vector_type(8)));
typedef float  f32x4  __attribute__((ext_vector_type(4)));

__device__ __forceinline__ unsigned short f2bf(float f) {
    union { float f; unsigned int u; } c; c.f = f;
    unsigned int u = c.u;
    u += 0x7fffu + ((u >> 16) & 1u);   // round-to-nearest-even
    return (unsigned short)(u >> 16);
}

// out[i] = x[i] @ W[tv[i]] + bias[tv[i]]  (tv sorted, T=16, D=128)
__global__ __launch_bounds__(256, 3) void hetero_lin_kernel(
    const float* __restrict__ x,
    const int*   __restrict__ tv,
    const float* __restrict__ w,      // [T][128][128]  (k-major, n contiguous)
    const float* __restrict__ bias,   // [T][128]
    float*       __restrict__ out,    // [N][128]
    int nrows)
{
    __shared__ unsigned short As[BM * LDA];   // x tile, bf16 [m][k]
    __shared__ unsigned short Bs[DD * LDB];   // W[t]^T,  bf16 [n][k]

    const int tid  = threadIdx.x;
    const int row0 = blockIdx.x * BM;

    const int t0 = tv[row0];
    const int t1 = tv[row0 + BM - 1];
    const bool uniform = (t0 == t1);

    // ---- Stage A: 64x128 fp32 -> bf16 LDS, coalesced float4 loads ----
    {
        const float4* xg = (const float4*)(x + (size_t)row0 * DD);
        #pragma unroll
        for (int i = 0; i < 8; ++i) {
            int f  = tid + i * 256;      // float4 index within tile
            int r  = f >> 5;             // 32 float4 per row
            int c4 = (f & 31) << 2;
            float4 v = xg[f];
            ushort4 pk;
            pk.x = f2bf(v.x); pk.y = f2bf(v.y); pk.z = f2bf(v.z); pk.w = f2bf(v.w);
            *(ushort4*)&As[r * LDA + c4] = pk;
        }
    }

    const int wave = tid >> 6;
    const int lane = tid & 63;
    const int q    = lane >> 4;
    const int n16  = lane & 15;
    // B-transpose mapping: k across lanes (so LDS scatter writes spread banks)
    const int k0l = (tid & 31) << 2;   // 0..124, step 4
    const int ng  = tid >> 5;          // 0..7

    for (int t = t0; t <= t1; ++t) {
        if (t > t0) __syncthreads();   // all waves done reading old Bs

        // ---- Stage B: W[t] fp32 [k][n] -> Bs bf16 [n][k] via 4x4 reg transpose ----
        {
            const float* wt = w + (size_t)t * DD * DD;
            #pragma unroll
            for (int i = 0; i < 4; ++i) {
                int n0 = (ng + (i << 3)) << 2;   // n-block 0..31
                float4 r0 = *(const float4*)&wt[(k0l + 0) * DD + n0];
                float4 r1 = *(const float4*)&wt[(k0l + 1) * DD + n0];
                float4 r2 = *(const float4*)&wt[(k0l + 2) * DD + n0];
                float4 r3 = *(const float4*)&wt[(k0l + 3) * DD + n0];
                ushort4 c0, c1, c2, c3;
                c0.x=f2bf(r0.x); c0.y=f2bf(r1.x); c0.z=f2bf(r2.x); c0.w=f2bf(r3.x);
                c1.x=f2bf(r0.y); c1.y=f2bf(r1.y); c1.z=f2bf(r2.y); c1.w=f2bf(r3.y);
                c2.x=f2bf(r0.z); c2.y=f2bf(r1.z); c2.z=f2bf(r2.z); c2.w=f2bf(r3.z);
                c3.x=f2bf(r0.w); c3.y=f2bf(r1.w); c3.z=f2bf(r2.w); c3.w=f2bf(r3.w);
                *(ushort4*)&Bs[(n0 + 0) * LDB + k0l] = c0;
                *(ushort4*)&Bs[(n0 + 1) * LDB + k0l] = c1;
                *(ushort4*)&Bs[(n0 + 2) * LDB + k0l] = c2;
                *(ushort4*)&Bs[(n0 + 3) * LDB + k0l] = c3;
            }
        }
        __syncthreads();

        // ---- MFMA: each wave -> rows wave*16..+15, all 128 cols ----
        f32x4 acc[8];
        #pragma unroll
        for (int nt = 0; nt < 8; ++nt) acc[nt] = (f32x4){0.f, 0.f, 0.f, 0.f};

        const unsigned short* arow = &As[(wave * 16 + n16) * LDA];
        #pragma unroll
        for (int kk = 0; kk < 4; ++kk) {
            bf16x8 a = *(const bf16x8*)&arow[kk * 32 + q * 8];
            #pragma unroll
            for (int nt = 0; nt < 8; ++nt) {
                bf16x8 b = *(const bf16x8*)&Bs[(nt * 16 + n16) * LDB + kk * 32 + q * 8];
                acc[nt] = __builtin_amdgcn_mfma_f32_16x16x32_bf16(a, b, acc[nt], 0, 0, 0);
            }
        }

        // ---- Epilogue: + bias, store fp32 (masked rows if block spans types) ----
        const int rbase = row0 + wave * 16 + q * 4;   // C/D: row = q*4 + reg
        bool m0 = true, m1 = true, m2 = true, m3 = true;
        if (!uniform) {
            m0 = (tv[rbase + 0] == t);
            m1 = (tv[rbase + 1] == t);
            m2 = (tv[rbase + 2] == t);
            m3 = (tv[rbase + 3] == t);
        }
        #pragma unroll
        for (int nt = 0; nt < 8; ++nt) {
            int col  = nt * 16 + n16;                  // C/D: col = lane&15
            float bv = bias[t * DD + col];
            float* o = out + (size_t)rbase * DD + col;
            if (m0) o[0 * DD] = acc[nt][0] + bv;
            if (m1) o[1 * DD] = acc[nt][1] + bv;
            if (m2) o[2 * DD] = acc[nt][2] + bv;
            if (m3) o[3 * DD] = acc[nt][3] + bv;
        }
    }
}

extern "C" void kernel_launch(void* const* d_in, const int* in_sizes, int n_in,
                              void* d_out, int out_size, void* d_ws, size_t ws_size,
                              hipStream_t stream) {
    const float* x    = (const float*)d_in[0];
    const int*   tv   = (const int*)d_in[1];
    const float* w    = (const float*)d_in[2];
    const float* bias = (const float*)d_in[3];
    float*       out  = (float*)d_out;
    int nrows = in_sizes[0] / DD;          // 131072
    int grid  = nrows / BM;                // 2048 (N divides BM exactly)
    hipLaunchKernelGGL(hetero_lin_kernel, dim3(grid), dim3(256), 0, stream,
                       x, tv, w, bias, out, nrows);
}